// Round 8
// baseline (118.808 us; speedup 1.0000x reference)
//
#include <hip/hip_runtime.h>

#define NROWS 8192
#define NSPLIT 8
#define JT (NROWS / NSPLIT)  // 1024 j's per split
#define NITER (JT / 64)      // 16
#define L2E 1.4426950408889634f

typedef __attribute__((ext_vector_type(4))) float f32x4;
typedef __attribute__((ext_vector_type(8))) __bf16 bf16x8;
typedef __attribute__((ext_vector_type(4))) unsigned int u32x4;

__device__ __forceinline__ unsigned short f2bf(float x) {
  unsigned u = __float_as_uint(x);
  u += 0x7fffu + ((u >> 16) & 1u);
  return (unsigned short)(u >> 16);
}

// ---------------------------------------------------------------------------
// Kernel A: Wh = h@W (stored bf16 in MFMA-B-fragment order), src=Wh@a1, dst=Wh@a2
// src/dst pre-scaled by log2(e) so downstream works in exp2 domain.
// Fragment layout: slot (jc, nt, lane, e) holds Wh[j = 32*jc + 8*(lane>>4) + e][nt*16 + (lane&15)]
// ---------------------------------------------------------------------------
__global__ __launch_bounds__(256) void k_prep(
    const float* __restrict__ h, const float* __restrict__ W,
    const float* __restrict__ a, unsigned short* __restrict__ WhB,
    float* __restrict__ src, float* __restrict__ dst) {
  int i = blockIdx.x * 4 + (threadIdx.x >> 6);  // row
  int lane = threadIdx.x & 63;                  // feature
  const float* hrow = h + (size_t)i * 256;
  float s = 0.f;
#pragma unroll 4
  for (int k = 0; k < 256; k += 4) {
    float4 hv = *(const float4*)(hrow + k);
    s = fmaf(hv.x, W[(k + 0) * 64 + lane], s);
    s = fmaf(hv.y, W[(k + 1) * 64 + lane], s);
    s = fmaf(hv.z, W[(k + 2) * 64 + lane], s);
    s = fmaf(hv.w, W[(k + 3) * 64 + lane], s);
  }
  int nt = lane >> 4, c = lane & 15;
  int gi = (i >> 3) & 3, e = i & 7;
  int idx = ((((i >> 5) * 4 + nt) * 64) + c + 16 * gi) * 8 + e;
  WhB[idx] = f2bf(s);
  float v1 = s * a[lane];
  float v2 = s * a[64 + lane];
#pragma unroll
  for (int d = 32; d; d >>= 1) {
    v1 += __shfl_xor(v1, d);
    v2 += __shfl_xor(v2, d);
  }
  if (lane == 0) {
    src[i] = v1 * L2E;
    dst[i] = v2 * L2E;
  }
}

// ---------------------------------------------------------------------------
// Kernel A2: dmax = max_j dst[j]  (global scalar; 1 block)
// ---------------------------------------------------------------------------
__global__ __launch_bounds__(256) void k_dmax(
    const float* __restrict__ dst, float* __restrict__ dmax) {
  __shared__ float red[4];
  float v = -INFINITY;
  for (int i = threadIdx.x; i < NROWS; i += 256) v = fmaxf(v, dst[i]);
#pragma unroll
  for (int d = 32; d; d >>= 1) v = fmaxf(v, __shfl_xor(v, d));
  if ((threadIdx.x & 63) == 0) red[threadIdx.x >> 6] = v;
  __syncthreads();
  if (threadIdx.x == 0)
    *dmax = fmaxf(fmaxf(red[0], red[1]), fmaxf(red[2], red[3]));
}

// ---------------------------------------------------------------------------
// Kernel B (FUSED): in-wave ballot-pack of adj + masked-softmax + PV.
// Phase 1 unchanged from R7 (coalesced ballots -> 4 u64 masks per lane).
// Phase 2 REWORKED: rolled outer loop, 32-col halves, named double-buffered
// B fragments prefetched one half ahead (L2 latency hides under compute),
// K=32 MFMA granularity, ~95 VGPR => no spill at 4 waves/SIMD.
// ---------------------------------------------------------------------------
__global__ __launch_bounds__(256, 4) void k_attn(
    const int* __restrict__ adj, const unsigned short* __restrict__ WhB,
    const float* __restrict__ src, const float* __restrict__ dst,
    const float* __restrict__ dmax,
    float* __restrict__ pl, float* __restrict__ pacc) {
  __shared__ float ldst[JT];
  int task = blockIdx.x * 4 + (threadIdx.x >> 6);  // 0 .. 512*NSPLIT-1
  int sp = task >> 9;                              // split (same for whole block)
  int mt = task & 511;                             // M-tile index
  int lane = threadIdx.x & 63;
  int r = lane & 15;  // row within tile / C col
  int g = lane >> 4;  // k-slot group
  int row0 = mt * 16;
  int jbase = sp * JT;

  // stage this split's dst slice to LDS (block-shared)
  for (int k = threadIdx.x; k < JT; k += 256) ldst[k] = dst[jbase + k];
  __syncthreads();

  // ---- Phase 1: ballot-pack 16 rows x 1024 cols into 4 u64 regs/lane ----
  unsigned long long mk0 = 0, mk1 = 0, mk2 = 0, mk3 = 0;
  {
    const int* abase = adj + (size_t)row0 * NROWS + jbase + lane;
#pragma unroll
    for (int rr = 0; rr < 16; ++rr) {
      const int* rp = abase + (size_t)rr * NROWS;
#pragma unroll
      for (int ch = 0; ch < 16; ++ch) {
        int v = rp[ch * 64];
        unsigned long long bal = __ballot(v > 0);
        const int holder = ((ch & 3) << 4) + rr;
        if ((ch >> 2) == 0) mk0 = (lane == holder) ? bal : mk0;
        if ((ch >> 2) == 1) mk1 = (lane == holder) ? bal : mk1;
        if ((ch >> 2) == 2) mk2 = (lane == holder) ? bal : mk2;
        if ((ch >> 2) == 3) mk3 = (lane == holder) ? bal : mk3;
      }
    }
  }

  float srcr = src[row0 + r];
  float vB = srcr + *dmax;
  float Mi = fmaxf(vB, 0.2f * vB);  // upper bound on this row's scores

  float lrA = 0.f, lrB = 0.f;
  f32x4 acc[4] = {f32x4{0.f, 0.f, 0.f, 0.f}, f32x4{0.f, 0.f, 0.f, 0.f},
                  f32x4{0.f, 0.f, 0.f, 0.f}, f32x4{0.f, 0.f, 0.f, 0.f}};
  const bf16x8* Bfr = (const bf16x8*)WhB;
  const int jc0 = jbase >> 5;  // first 32-col tile of this split

  // one 32-col half: 8 PE -> pack -> 4 MFMA (K=32)
#define HALF(B0, B1, B2, B3, BITS, DOFF)                                   \
  {                                                                        \
    const float4* dlp = (const float4*)(ldst + (DOFF));                    \
    float4 dA = dlp[0];                                                    \
    float4 dB = dlp[1];                                                    \
    unsigned bt_ = (BITS);                                                 \
    float p0, p1, p2, p3, p4, p5, p6, p7;                                  \
    PE(p0, bt_ & 1u, dA.x)   PE(p1, bt_ & 2u, dA.y)                        \
    PE(p2, bt_ & 4u, dA.z)   PE(p3, bt_ & 8u, dA.w)                        \
    PE(p4, bt_ & 16u, dB.x)  PE(p5, bt_ & 32u, dB.y)                       \
    PE(p6, bt_ & 64u, dB.z)  PE(p7, bt_ & 128u, dB.w)                      \
    lrA += (p0 + p1) + (p2 + p3);                                          \
    lrB += (p4 + p5) + (p6 + p7);                                          \
    unsigned q0, q1, q2, q3;                                               \
    asm("v_cvt_pk_bf16_f32 %0, %1, %2" : "=v"(q0) : "v"(p0), "v"(p1));     \
    asm("v_cvt_pk_bf16_f32 %0, %1, %2" : "=v"(q1) : "v"(p2), "v"(p3));     \
    asm("v_cvt_pk_bf16_f32 %0, %1, %2" : "=v"(q2) : "v"(p4), "v"(p5));     \
    asm("v_cvt_pk_bf16_f32 %0, %1, %2" : "=v"(q3) : "v"(p6), "v"(p7));     \
    u32x4 qv = {q0, q1, q2, q3};                                           \
    bf16x8 Af = __builtin_bit_cast(bf16x8, qv);                            \
    __builtin_amdgcn_s_setprio(1);                                         \
    acc[0] = __builtin_amdgcn_mfma_f32_16x16x32_bf16(Af, B0, acc[0], 0, 0, 0); \
    acc[1] = __builtin_amdgcn_mfma_f32_16x16x32_bf16(Af, B1, acc[1], 0, 0, 0); \
    acc[2] = __builtin_amdgcn_mfma_f32_16x16x32_bf16(Af, B2, acc[2], 0, 0, 0); \
    acc[3] = __builtin_amdgcn_mfma_f32_16x16x32_bf16(Af, B3, acc[3], 0, 0, 0); \
    __builtin_amdgcn_s_setprio(0);                                         \
  }
#define PE(P, BIT, DD)                    \
  {                                       \
    float v_ = srcr + (DD);               \
    v_ = fmaxf(v_, 0.2f * v_);            \
    float e_ = exp2f(v_ - Mi);            \
    (P) = (BIT) ? e_ : 0.f;               \
  }

  // prologue: bbA <- half 0
  const bf16x8* bpA = Bfr + (size_t)jc0 * 256 + lane;
  bf16x8 a0 = bpA[0], a1 = bpA[64], a2 = bpA[128], a3 = bpA[192];

#pragma unroll 1
  for (int it = 0; it < NITER; ++it) {
    // mask(r, it): one cross-lane fetch per 64 cols
    int sel = it >> 2;
    unsigned long long msrc = (sel == 0) ? mk0
                            : (sel == 1) ? mk1
                            : (sel == 2) ? mk2 : mk3;
    unsigned long long pw = __shfl(msrc, ((it & 3) << 4) + r);

    // prefetch bbB <- half 2*it+1 (consumed later this iter)
    const bf16x8* bpB = Bfr + (size_t)(jc0 + 2 * it + 1) * 256 + lane;
    bf16x8 c0 = bpB[0], c1 = bpB[64], c2 = bpB[128], c3 = bpB[192];
    __builtin_amdgcn_sched_barrier(0);

    // compute half 2*it with bbA (waits only on older bbA loads)
    HALF(a0, a1, a2, a3, (unsigned)(pw >> (8 * g)), it * 64 + 8 * g)

    // prefetch bbA <- half 2*it+2 (next iter; wrap harmlessly at end)
    int jn = (it == NITER - 1) ? jc0 : jc0 + 2 * it + 2;
    const bf16x8* bpN = Bfr + (size_t)jn * 256 + lane;
    a0 = bpN[0]; a1 = bpN[64]; a2 = bpN[128]; a3 = bpN[192];
    __builtin_amdgcn_sched_barrier(0);

    // compute half 2*it+1 with bbB (waits only on older bbB loads)
    HALF(c0, c1, c2, c3, (unsigned)(pw >> (32 + 8 * g)), it * 64 + 32 + 8 * g)
  }
#undef PE
#undef HALF

  // row-sum of l across the 4 g-groups (lanes r, r+16, r+32, r+48)
  float lrow = lrA + lrB;
  lrow += __shfl_xor(lrow, 16);
  lrow += __shfl_xor(lrow, 32);
  if (lane < 16) pl[sp * NROWS + row0 + lane] = lrow;
#pragma unroll
  for (int nt = 0; nt < 4; nt++)
#pragma unroll
    for (int q2 = 0; q2 < 4; q2++)
      pacc[((size_t)sp * NROWS + row0 + 4 * g + q2) * 64 + nt * 16 + r] = acc[nt][q2];
}

// ---------------------------------------------------------------------------
// Kernel C: combine = plain sums (all splits share the same reference Mi).
// ---------------------------------------------------------------------------
__global__ __launch_bounds__(256) void k_comb(
    const float* __restrict__ pl, const float* __restrict__ pacc,
    float* __restrict__ out) {
  int t = blockIdx.x * 256 + threadIdx.x;
  int row = t >> 6, f = t & 63;
  float L = 0.f, o = 0.f;
#pragma unroll
  for (int s2 = 0; s2 < NSPLIT; s2++) {
    L += pl[s2 * NROWS + row];
    o += pacc[((size_t)s2 * NROWS + row) * 64 + f];
  }
  out[t] = o / L;
}

extern "C" void kernel_launch(void* const* d_in, const int* in_sizes, int n_in,
                              void* d_out, int out_size, void* d_ws, size_t ws_size,
                              hipStream_t stream) {
  const float* h = (const float*)d_in[0];
  const float* W = (const float*)d_in[1];
  const float* a = (const float*)d_in[2];
  const int* adj = (const int*)d_in[3];
  float* out = (float*)d_out;

  char* ws = (char*)d_ws;
  unsigned short* WhB = (unsigned short*)ws;           // 1 MB
  float* src = (float*)(ws + 0x100000);                // 32 KB
  float* dst = (float*)(ws + 0x108000);                // 32 KB
  float* dmax = (float*)(ws + 0x110000);               // 256 B
  float* pl = (float*)(ws + 0x110100);                 // 256 KB
  float* pacc = (float*)(ws + 0x150100);               // 16 MB

  hipLaunchKernelGGL(k_prep, dim3(NROWS / 4), dim3(256), 0, stream, h, W, a, WhB, src, dst);
  hipLaunchKernelGGL(k_dmax, dim3(1), dim3(256), 0, stream, dst, dmax);
  hipLaunchKernelGGL(k_attn, dim3(512 * NSPLIT / 4), dim3(256), 0, stream,
                     adj, WhB, src, dst, dmax, pl, pacc);
  hipLaunchKernelGGL(k_comb, dim3(NROWS * 64 / 256), dim3(256), 0, stream, pl, pacc, out);
}